// Round 11
// baseline (10440.047 us; speedup 1.0000x reference)
//
#include <hip/hip_runtime.h>
#include <math.h>

// ESN reservoir: B=1, T=2048, I=8, R=4096, O=8.
// h_t = tanh(Win x_t + W h_{t-1}); y_t = Wout h_t + b.
//
// R11: ONE-hop sync. h published as self-validating 8-B packets
// (tag<<32 | h_bits), tag = epoch*4096 + t + 1 (epoch bumped per launch).
// Producer: fire-and-forget system-scope packet stores (no drain, no flag,
// no trailing hop -- the next poll's vmcnt(0) drains them for free).
// Consumer: thread i owns 8 contiguous packets (64 B); do{4 pipelined
// dwordx4 sc0 sc1; check tags; s_sleep backoff}while stale. The divergent
// loop masks off finished lanes -> retry traffic only from stale lanes
// (R6 collapse = full re-read, no backoff; R7 = no backoff).
// Geometry from R10 (proven): 128 WGs x 512 thr, 32 rows/WG, pool in LDS.
// NUMERICS BIT-IDENTICAL to R4..R10: 16 thr/row, stride-16 entry order,
// same shfl tree, same Win/tanh, R6's packet out-kernel.

#define T_STEPS 2048
#define R_DIM   4096
#define I_DIM   8
#define O_DIM   8
#define NWG     128
#define ROWS_PER_WG (R_DIM / NWG)   // 32
#define POOL_CAP 16384              // mean nnz/WG = 13107, ~30 sigma headroom
#define BLOCK    512                // 16 threads/row x 32 rows
#define TAG_MUL  4096

typedef unsigned int v4u __attribute__((ext_vector_type(4)));

__device__ unsigned long long g_pack[(size_t)T_STEPS * R_DIM];  // 64 MB
__device__ unsigned int      g_epoch;

__global__ void esn_init_kernel() {
    if (threadIdx.x == 0) {
        unsigned e = __hip_atomic_load(&g_epoch, __ATOMIC_RELAXED,
                                       __HIP_MEMORY_SCOPE_SYSTEM) + 1u;
        __hip_atomic_store(&g_epoch, e, __ATOMIC_RELAXED,
                           __HIP_MEMORY_SCOPE_SYSTEM);
    }
}

__launch_bounds__(BLOCK, 1)
__global__ void esn_recur_kernel(const float* __restrict__ x,
                                 const float* __restrict__ Win,
                                 const float* __restrict__ W) {
    __shared__ uint2 s_pool[POOL_CAP];                // 128 KB (val bits, idx)
    __shared__ float s_h[R_DIM];                      // 16 KB
    __shared__ int   s_start[ROWS_PER_WG + 1];
    __shared__ int   s_cnt[ROWS_PER_WG];
    __shared__ float s_win[ROWS_PER_WG][I_DIM];

    const int wg   = blockIdx.x;
    const int tid  = threadIdx.x;
    const int lane = tid & 63;
    const int wave = tid >> 6;          // 0..7
    const int row0 = wg * ROWS_PER_WG;

    const unsigned tag_base =
        __hip_atomic_load(&g_epoch, __ATOMIC_RELAXED,
                          __HIP_MEMORY_SCOPE_SYSTEM) * TAG_MUL;

    // ---------- one-time setup: compact 32 rows of W into LDS ----------
    // (per-row entry order identical to R4: ballot-compaction, column order)
    for (int rr = wave; rr < ROWS_PER_WG; rr += 8) {
        const float* wrow = W + (size_t)(row0 + rr) * R_DIM;
        int cnt = 0;
        for (int base = 0; base < R_DIM; base += 64) {
            float v = wrow[base + lane];
            cnt += __popcll(__ballot(v != 0.0f));
        }
        if (lane == 0) s_cnt[rr] = cnt;
    }
    __syncthreads();
    if (tid == 0) {
        int acc = 0;
        for (int rr = 0; rr < ROWS_PER_WG; ++rr) {
            s_start[rr] = (acc < POOL_CAP) ? acc : POOL_CAP;
            acc += s_cnt[rr];
        }
        s_start[ROWS_PER_WG] = (acc < POOL_CAP) ? acc : POOL_CAP;
    }
    __syncthreads();
    for (int rr = wave; rr < ROWS_PER_WG; rr += 8) {
        const float* wrow = W + (size_t)(row0 + rr) * R_DIM;
        int off = s_start[rr];
        for (int base = 0; base < R_DIM; base += 64) {
            float v = wrow[base + lane];
            unsigned long long m = __ballot(v != 0.0f);
            int pre = __popcll(m & ((1ull << lane) - 1ull));
            if (v != 0.0f) {
                int pos = off + pre;
                if (pos < POOL_CAP) {
                    s_pool[pos].x = __float_as_uint(v);
                    s_pool[pos].y = base + lane;
                }
            }
            off += __popcll(m);
        }
    }
    if (tid < ROWS_PER_WG * I_DIM) {
        int rr = tid / I_DIM, c = tid % I_DIM;
        s_win[rr][c] = Win[(size_t)(row0 + rr) * I_DIM + c];
    }
    __syncthreads();

    const int row16 = tid >> 4;          // 0..31: which of my 32 rows
    const int sub   = tid & 15;          // 16 threads per row (as R4)
    const int start = s_start[row16];
    const int cnt   = s_start[row16 + 1] - start;

    // ---------- time loop ----------
    for (int t = 0; t < T_STEPS; ++t) {
        if (t > 0) {
            const unsigned exp_tag = tag_base + (unsigned)t;  // packets of t-1
            // poll my 8 contiguous packets (64 B); stale lanes only re-issue
            const unsigned long long* bp =
                g_pack + (size_t)(t - 1) * R_DIM + tid * 8;
            v4u q0, q1, q2, q3;
            bool ok;
            do {
                asm volatile(
                    "global_load_dwordx4 %0, %4, off sc0 sc1\n\t"
                    "global_load_dwordx4 %1, %4, off offset:16 sc0 sc1\n\t"
                    "global_load_dwordx4 %2, %4, off offset:32 sc0 sc1\n\t"
                    "global_load_dwordx4 %3, %4, off offset:48 sc0 sc1\n\t"
                    "s_waitcnt vmcnt(0)"
                    : "=v"(q0), "=v"(q1), "=v"(q2), "=v"(q3)
                    : "v"(bp)
                    : "memory");
                ok = (q0.y == exp_tag) & (q0.w == exp_tag) &
                     (q1.y == exp_tag) & (q1.w == exp_tag) &
                     (q2.y == exp_tag) & (q2.w == exp_tag) &
                     (q3.y == exp_tag) & (q3.w == exp_tag);
                if (!ok) __builtin_amdgcn_s_sleep(4);
            } while (!ok);
            // deposit 8 consecutive h values
            float2* d2 = (float2*)(s_h + tid * 8);
            d2[0] = make_float2(__uint_as_float(q0.x), __uint_as_float(q0.z));
            d2[1] = make_float2(__uint_as_float(q1.x), __uint_as_float(q1.z));
            d2[2] = make_float2(__uint_as_float(q2.x), __uint_as_float(q2.z));
            d2[3] = make_float2(__uint_as_float(q3.x), __uint_as_float(q3.z));
            __syncthreads();
        }

        // sparse row-dot: identical per-row order to R4..R10 (16 lanes, stride 16)
        float acc = 0.0f;
        if (t > 0) {
            for (int e = start + sub; e < start + cnt; e += 16) {
                uint2 p = s_pool[e];
                acc += __uint_as_float(p.x) * s_h[p.y];
            }
        }
        acc += __shfl_xor(acc, 8, 16);
        acc += __shfl_xor(acc, 4, 16);
        acc += __shfl_xor(acc, 2, 16);
        acc += __shfl_xor(acc, 1, 16);

        if (sub == 0) {
            const float* xt = x + (size_t)t * I_DIM;
            float a = acc;
            #pragma unroll
            for (int c = 0; c < I_DIM; ++c) a += s_win[row16][c] * xt[c];
            float h = tanhf(a);
            unsigned long long pk =
                ((unsigned long long)(tag_base + (unsigned)(t + 1)) << 32) |
                (unsigned long long)__float_as_uint(h);
            // fire-and-forget: next step's poll vmcnt(0) drains this store
            __hip_atomic_store(&g_pack[(size_t)t * R_DIM + row0 + row16], pk,
                               __ATOMIC_RELAXED, __HIP_MEMORY_SCOPE_SYSTEM);
        }
        __syncthreads();   // all s_h readers done before next deposit
    }
}

// y_t = Wout h_t + b, one wave per timestep; accumulation order as R4..R10.
__global__ void esn_out_kernel(const float* __restrict__ Wout_w,
                               const float* __restrict__ Wout_b,
                               float* __restrict__ out) {
    const int t = blockIdx.x;
    const int lane = threadIdx.x;  // 64 threads
    const unsigned long long* hp = g_pack + (size_t)t * R_DIM;
    float acc[O_DIM];
    #pragma unroll
    for (int o = 0; o < O_DIM; ++o) acc[o] = 0.0f;
    for (int i = lane; i < R_DIM; i += 256) {   // 16 iters, 4 indep loads each
        unsigned long long u0 = __hip_atomic_load(hp + i,       __ATOMIC_RELAXED, __HIP_MEMORY_SCOPE_SYSTEM);
        unsigned long long u1 = __hip_atomic_load(hp + i + 64,  __ATOMIC_RELAXED, __HIP_MEMORY_SCOPE_SYSTEM);
        unsigned long long u2 = __hip_atomic_load(hp + i + 128, __ATOMIC_RELAXED, __HIP_MEMORY_SCOPE_SYSTEM);
        unsigned long long u3 = __hip_atomic_load(hp + i + 192, __ATOMIC_RELAXED, __HIP_MEMORY_SCOPE_SYSTEM);
        float h0 = __uint_as_float((unsigned)u0);
        float h1 = __uint_as_float((unsigned)u1);
        float h2 = __uint_as_float((unsigned)u2);
        float h3 = __uint_as_float((unsigned)u3);
        #pragma unroll
        for (int o = 0; o < O_DIM; ++o) acc[o] += h0 * Wout_w[(size_t)o * R_DIM + i];
        #pragma unroll
        for (int o = 0; o < O_DIM; ++o) acc[o] += h1 * Wout_w[(size_t)o * R_DIM + i + 64];
        #pragma unroll
        for (int o = 0; o < O_DIM; ++o) acc[o] += h2 * Wout_w[(size_t)o * R_DIM + i + 128];
        #pragma unroll
        for (int o = 0; o < O_DIM; ++o) acc[o] += h3 * Wout_w[(size_t)o * R_DIM + i + 192];
    }
    #pragma unroll
    for (int o = 0; o < O_DIM; ++o) {
        float a = acc[o];
        a += __shfl_xor(a, 32);
        a += __shfl_xor(a, 16);
        a += __shfl_xor(a, 8);
        a += __shfl_xor(a, 4);
        a += __shfl_xor(a, 2);
        a += __shfl_xor(a, 1);
        if (lane == 0) out[(size_t)t * O_DIM + o] = a + Wout_b[o];
    }
}

extern "C" void kernel_launch(void* const* d_in, const int* in_sizes, int n_in,
                              void* d_out, int out_size, void* d_ws, size_t ws_size,
                              hipStream_t stream) {
    const float* x    = (const float*)d_in[0];   // [1,2048,8]
    const float* Win  = (const float*)d_in[1];   // [4096,8]
    const float* W    = (const float*)d_in[2];   // [4096,4096]
    const float* Ww   = (const float*)d_in[3];   // [8,4096]
    const float* Wb   = (const float*)d_in[4];   // [8]
    float* out = (float*)d_out;                  // [1,2048,8]

    hipLaunchKernelGGL(esn_init_kernel, dim3(1), dim3(64), 0, stream);

    void* args[] = { (void*)&x, (void*)&Win, (void*)&W };
    hipLaunchCooperativeKernel((void*)esn_recur_kernel, dim3(NWG), dim3(BLOCK),
                               args, 0, stream);

    hipLaunchKernelGGL(esn_out_kernel, dim3(T_STEPS), dim3(64), 0, stream,
                       Ww, Wb, out);
}

// Round 12
// 8599.965 us; speedup vs baseline: 1.2140x; 1.2140x over previous
//
#include <hip/hip_runtime.h>
#include <math.h>

// ESN reservoir: B=1, T=2048, I=8, R=4096, O=8.
// h_t = tanh(Win x_t + W h_{t-1}); y_t = Wout h_t + b.
//
// R12 = R10 (best: 8.8 ms steady; 128 WGs x 512 thr, 32 rows/WG, sparse W
// pool in LDS, per-WG flag on own 128-B line, one-shot bypass broadcast)
// + three critical-path trims, numerics bit-identical:
//  1. wave-granular poll: each wave polls only the 16 flag lines covering
//     the 512 h values it deposits (lanes 0-15, __all exit) -> kills the
//     WG-wide poll barrier, lets early waves read while late producers land.
//     Poll traffic unchanged (128 pollers/line, as R10).
//  2. x_t prefetched before the poll (was a dependent load after reduce).
//  3. s_sleep(1) backoff (finer discovery).
// R11's tag-packet scheme regressed (data-polling traffic > 1 saved hop);
// flags + one-shot read is the converged structure.

#define T_STEPS 2048
#define R_DIM   4096
#define I_DIM   8
#define O_DIM   8
#define NWG     128
#define ROWS_PER_WG (R_DIM / NWG)   // 32
#define POOL_CAP 16384              // mean nnz/WG = 13107, ~30 sigma headroom
#define BLOCK    512                // 16 threads/row x 32 rows

typedef float v4f __attribute__((ext_vector_type(4)));

__device__ float        g_hist[(size_t)T_STEPS * R_DIM];  // 32 MB
__device__ unsigned int g_flag[NWG * 32];                 // one 128-B line per WG

__global__ void esn_init_kernel() {
    for (int i = threadIdx.x; i < NWG * 32; i += blockDim.x)
        __hip_atomic_store(&g_flag[i], 0u, __ATOMIC_RELAXED,
                           __HIP_MEMORY_SCOPE_SYSTEM);
}

__launch_bounds__(BLOCK, 1)
__global__ void esn_recur_kernel(const float* __restrict__ x,
                                 const float* __restrict__ Win,
                                 const float* __restrict__ W) {
    __shared__ uint2 s_pool[POOL_CAP];                // 128 KB (val bits, idx)
    __shared__ float s_h[R_DIM];                      // 16 KB
    __shared__ int   s_start[ROWS_PER_WG + 1];
    __shared__ int   s_cnt[ROWS_PER_WG];
    __shared__ float s_win[ROWS_PER_WG][I_DIM];

    const int wg   = blockIdx.x;
    const int tid  = threadIdx.x;
    const int lane = tid & 63;
    const int wave = tid >> 6;          // 0..7
    const int row0 = wg * ROWS_PER_WG;

    // ---------- one-time setup: compact 32 rows of W into LDS ----------
    // (per-row entry order identical to R4: ballot-compaction, column order)
    for (int rr = wave; rr < ROWS_PER_WG; rr += 8) {
        const float* wrow = W + (size_t)(row0 + rr) * R_DIM;
        int cnt = 0;
        for (int base = 0; base < R_DIM; base += 64) {
            float v = wrow[base + lane];
            cnt += __popcll(__ballot(v != 0.0f));
        }
        if (lane == 0) s_cnt[rr] = cnt;
    }
    __syncthreads();
    if (tid == 0) {
        int acc = 0;
        for (int rr = 0; rr < ROWS_PER_WG; ++rr) {
            s_start[rr] = (acc < POOL_CAP) ? acc : POOL_CAP;
            acc += s_cnt[rr];
        }
        s_start[ROWS_PER_WG] = (acc < POOL_CAP) ? acc : POOL_CAP;
    }
    __syncthreads();
    for (int rr = wave; rr < ROWS_PER_WG; rr += 8) {
        const float* wrow = W + (size_t)(row0 + rr) * R_DIM;
        int off = s_start[rr];
        for (int base = 0; base < R_DIM; base += 64) {
            float v = wrow[base + lane];
            unsigned long long m = __ballot(v != 0.0f);
            int pre = __popcll(m & ((1ull << lane) - 1ull));
            if (v != 0.0f) {
                int pos = off + pre;
                if (pos < POOL_CAP) {
                    s_pool[pos].x = __float_as_uint(v);
                    s_pool[pos].y = base + lane;
                }
            }
            off += __popcll(m);
        }
    }
    if (tid < ROWS_PER_WG * I_DIM) {
        int rr = tid / I_DIM, c = tid % I_DIM;
        s_win[rr][c] = Win[(size_t)(row0 + rr) * I_DIM + c];
    }
    __syncthreads();

    const int row16 = tid >> 4;          // 0..31: which of my 32 rows
    const int sub   = tid & 15;          // 16 threads per row (as R4)
    const int start = s_start[row16];
    const int cnt   = s_start[row16 + 1] - start;

    // wave-poll setup: wave w deposits h[w*512 .. w*512+511], i.e. the
    // output of source WGs [w*16, w*16+16). Lanes 0-15 poll one line each.
    const int  src_wg  = (wave << 4) + (lane & 15);
    const bool poller  = (lane < 16);
    const unsigned* fp = &g_flag[src_wg << 5];

    // ---------- time loop ----------
    for (int t = 0; t < T_STEPS; ++t) {
        // prefetch x_t (same values/order as before; just issued early)
        const float4* xp = (const float4*)(x + (size_t)t * I_DIM);
        const float4 xa = xp[0];
        const float4 xb = xp[1];

        if (t > 0) {
            const unsigned ut = (unsigned)t;
            // wave-granular readiness: my wave's 16 source lines only
            for (;;) {
                unsigned v = poller
                    ? __hip_atomic_load(fp, __ATOMIC_RELAXED,
                                        __HIP_MEMORY_SCOPE_SYSTEM)
                    : ut;
                if (__all(v >= ut)) break;
                __builtin_amdgcn_s_sleep(1);
            }
            // one-shot bypass read of my 32 B of h_{t-1}
            const v4f* bp = (const v4f*)(g_hist + (size_t)(t - 1) * R_DIM
                                         + (size_t)tid * 8);
            v4f r0, r1;
            asm volatile(
                "global_load_dwordx4 %0, %2, off sc0 sc1\n\t"
                "global_load_dwordx4 %1, %2, off offset:16 sc0 sc1\n\t"
                "s_waitcnt vmcnt(0)"
                : "=v"(r0), "=v"(r1)
                : "v"(bp)
                : "memory");
            v4f* dst = (v4f*)(s_h + (size_t)tid * 8);
            dst[0] = r0;
            dst[1] = r1;
            __syncthreads();
        }

        // sparse row-dot: identical per-row order to R4..R11 (16 lanes, stride 16)
        float acc = 0.0f;
        if (t > 0) {
            for (int e = start + sub; e < start + cnt; e += 16) {
                uint2 p = s_pool[e];
                acc += __uint_as_float(p.x) * s_h[p.y];
            }
        }
        acc += __shfl_xor(acc, 8, 16);
        acc += __shfl_xor(acc, 4, 16);
        acc += __shfl_xor(acc, 2, 16);
        acc += __shfl_xor(acc, 1, 16);

        if (sub == 0) {
            float a = acc;
            a += s_win[row16][0] * xa.x;
            a += s_win[row16][1] * xa.y;
            a += s_win[row16][2] * xa.z;
            a += s_win[row16][3] * xa.w;
            a += s_win[row16][4] * xb.x;
            a += s_win[row16][5] * xb.y;
            a += s_win[row16][6] * xb.z;
            a += s_win[row16][7] * xb.w;
            float h = tanhf(a);
            // write-through to coherence point (MALL)
            __hip_atomic_store(&g_hist[(size_t)t * R_DIM + row0 + row16], h,
                               __ATOMIC_RELAXED, __HIP_MEMORY_SCOPE_SYSTEM);
        }
        // release: drain own stores (acked at MALL), join WG, publish flag
        asm volatile("s_waitcnt vmcnt(0)" ::: "memory");
        __syncthreads();
        if (tid == 0)
            __hip_atomic_store(&g_flag[wg << 5], (unsigned)(t + 1),
                               __ATOMIC_RELAXED, __HIP_MEMORY_SCOPE_SYSTEM);
    }
}

// y_t = Wout h_t + b, one wave per timestep; accumulation order as R4..R11.
__global__ void esn_out_kernel(const float* __restrict__ Wout_w,
                               const float* __restrict__ Wout_b,
                               float* __restrict__ out) {
    const int t = blockIdx.x;
    const int lane = threadIdx.x;  // 64 threads
    const float* hp = g_hist + (size_t)t * R_DIM;
    float acc[O_DIM];
    #pragma unroll
    for (int o = 0; o < O_DIM; ++o) acc[o] = 0.0f;
    for (int i = lane; i < R_DIM; i += 256) {   // 16 iters, 4 indep loads each
        float h0 = __hip_atomic_load(hp + i,       __ATOMIC_RELAXED, __HIP_MEMORY_SCOPE_SYSTEM);
        float h1 = __hip_atomic_load(hp + i + 64,  __ATOMIC_RELAXED, __HIP_MEMORY_SCOPE_SYSTEM);
        float h2 = __hip_atomic_load(hp + i + 128, __ATOMIC_RELAXED, __HIP_MEMORY_SCOPE_SYSTEM);
        float h3 = __hip_atomic_load(hp + i + 192, __ATOMIC_RELAXED, __HIP_MEMORY_SCOPE_SYSTEM);
        #pragma unroll
        for (int o = 0; o < O_DIM; ++o) acc[o] += h0 * Wout_w[(size_t)o * R_DIM + i];
        #pragma unroll
        for (int o = 0; o < O_DIM; ++o) acc[o] += h1 * Wout_w[(size_t)o * R_DIM + i + 64];
        #pragma unroll
        for (int o = 0; o < O_DIM; ++o) acc[o] += h2 * Wout_w[(size_t)o * R_DIM + i + 128];
        #pragma unroll
        for (int o = 0; o < O_DIM; ++o) acc[o] += h3 * Wout_w[(size_t)o * R_DIM + i + 192];
    }
    #pragma unroll
    for (int o = 0; o < O_DIM; ++o) {
        float a = acc[o];
        a += __shfl_xor(a, 32);
        a += __shfl_xor(a, 16);
        a += __shfl_xor(a, 8);
        a += __shfl_xor(a, 4);
        a += __shfl_xor(a, 2);
        a += __shfl_xor(a, 1);
        if (lane == 0) out[(size_t)t * O_DIM + o] = a + Wout_b[o];
    }
}

extern "C" void kernel_launch(void* const* d_in, const int* in_sizes, int n_in,
                              void* d_out, int out_size, void* d_ws, size_t ws_size,
                              hipStream_t stream) {
    const float* x    = (const float*)d_in[0];   // [1,2048,8]
    const float* Win  = (const float*)d_in[1];   // [4096,8]
    const float* W    = (const float*)d_in[2];   // [4096,4096]
    const float* Ww   = (const float*)d_in[3];   // [8,4096]
    const float* Wb   = (const float*)d_in[4];   // [8]
    float* out = (float*)d_out;                  // [1,2048,8]

    hipLaunchKernelGGL(esn_init_kernel, dim3(1), dim3(256), 0, stream);

    void* args[] = { (void*)&x, (void*)&Win, (void*)&W };
    hipLaunchCooperativeKernel((void*)esn_recur_kernel, dim3(NWG), dim3(BLOCK),
                               args, 0, stream);

    hipLaunchKernelGGL(esn_out_kernel, dim3(T_STEPS), dim3(64), 0, stream,
                       Ww, Wb, out);
}

// Round 13
// 7061.008 us; speedup vs baseline: 1.4785x; 1.2180x over previous
//
#include <hip/hip_runtime.h>
#include <math.h>

// ESN reservoir: B=1, T=2048, I=8, R=4096, O=8.
// h_t = tanh(Win x_t + W h_{t-1}); y_t = Wout h_t + b.
//
// R13 = R12's converged sync structure (per-WG flag on own 128-B line,
// wave-granular poll, one-shot bypass broadcast, fire-drain-flag release)
// with participants halved and the W pool moved to REGISTERS:
//  - NWG=64 x 1024 threads, 64 rows/WG, STILL 16 threads/row (numerics
//    bit-identical: same entry->(thread,slot) map, same stride-16 order,
//    same shfl tree, same Win/tanh, same out kernel).
//  - per-thread pool: 36 static slots (val f32[36], idx-byte-addr packed
//    u16x2[18]); zero-pad tail = exact no-op (0*h[0], broadcast = free).
//    Eliminates ALL pool ds_read_b64 from the steady loop.
//  - setup: R12's ballot-compaction, run twice through the same 128 KB
//    LDS staging pool (rows 0..31, then 32..63), then copied to regs.
//  - poll: 64 pollers/line (was 128); broadcast 1 MB/step (was 2).

#define T_STEPS 2048
#define R_DIM   4096
#define I_DIM   8
#define O_DIM   8
#define NWG     64
#define ROWS_PER_WG (R_DIM / NWG)   // 64
#define HALF_ROWS 32                // rows per setup pass
#define POOL_CAP 16384              // staging for 32 rows (mean 13107 nnz)
#define BLOCK    1024               // 16 threads/row x 64 rows
#define NS       36                 // reg slots/thread (36*16=576 >= max cnt ~486)

typedef float v4f __attribute__((ext_vector_type(4)));

__device__ float        g_hist[(size_t)T_STEPS * R_DIM];  // 32 MB
__device__ unsigned int g_flag[NWG * 32];                 // one 128-B line per WG

__global__ void esn_init_kernel() {
    for (int i = threadIdx.x; i < NWG * 32; i += blockDim.x)
        __hip_atomic_store(&g_flag[i], 0u, __ATOMIC_RELAXED,
                           __HIP_MEMORY_SCOPE_SYSTEM);
}

__launch_bounds__(BLOCK, 1)
__global__ void esn_recur_kernel(const float* __restrict__ x,
                                 const float* __restrict__ Win,
                                 const float* __restrict__ W) {
    __shared__ uint2 s_pool[POOL_CAP];                // 128 KB staging (setup only)
    __shared__ float s_h[R_DIM];                      // 16 KB
    __shared__ int   s_start[HALF_ROWS + 1];
    __shared__ int   s_cnt[HALF_ROWS];
    __shared__ float s_win[ROWS_PER_WG][I_DIM];       // 2 KB

    const int wg   = blockIdx.x;
    const int tid  = threadIdx.x;
    const int lane = tid & 63;
    const int wave = tid >> 6;          // 0..15
    const int row0 = wg * ROWS_PER_WG;

    const int row16 = tid >> 4;          // 0..63: which of my 64 rows
    const int sub   = tid & 15;          // 16 threads per row (frozen)

    float    rv[NS];                     // per-slot values
    unsigned ri[NS / 2];                 // per-slot h byte-addresses, u16x2

    // ---------- setup: two passes of R12's ballot compaction ----------
    for (int pass = 0; pass < 2; ++pass) {
        const int prow0 = row0 + pass * HALF_ROWS;
        // count nnz: 16 waves cover 32 rows, 2 each
        for (int rr = wave; rr < HALF_ROWS; rr += 16) {
            const float* wrow = W + (size_t)(prow0 + rr) * R_DIM;
            int cnt = 0;
            for (int base = 0; base < R_DIM; base += 64) {
                float v = wrow[base + lane];
                cnt += __popcll(__ballot(v != 0.0f));
            }
            if (lane == 0) s_cnt[rr] = cnt;
        }
        __syncthreads();
        if (tid == 0) {
            int acc = 0;
            for (int rr = 0; rr < HALF_ROWS; ++rr) {
                s_start[rr] = (acc < POOL_CAP) ? acc : POOL_CAP;
                acc += s_cnt[rr];
            }
            s_start[HALF_ROWS] = (acc < POOL_CAP) ? acc : POOL_CAP;
        }
        __syncthreads();
        // fill staging pool (column order per row, as R4..R12)
        for (int rr = wave; rr < HALF_ROWS; rr += 16) {
            const float* wrow = W + (size_t)(prow0 + rr) * R_DIM;
            int off = s_start[rr];
            for (int base = 0; base < R_DIM; base += 64) {
                float v = wrow[base + lane];
                unsigned long long m = __ballot(v != 0.0f);
                int pre = __popcll(m & ((1ull << lane) - 1ull));
                if (v != 0.0f) {
                    int pos = off + pre;
                    if (pos < POOL_CAP) {
                        s_pool[pos].x = __float_as_uint(v);
                        s_pool[pos].y = (base + lane) * 4;   // byte addr
                    }
                }
                off += __popcll(m);
            }
        }
        __syncthreads();
        // copy my slots to registers (threads owning rows of this pass)
        const int lr = row16 - pass * HALF_ROWS;
        if (lr >= 0 && lr < HALF_ROWS) {
            const int st = s_start[lr];
            const int en = s_start[lr + 1];
            #pragma unroll
            for (int m = 0; m < NS; ++m) {
                const int e = st + sub + (m << 4);
                float    v = 0.0f;
                unsigned b = 0u;
                if (e < en) { uint2 p = s_pool[e]; v = __uint_as_float(p.x); b = p.y; }
                rv[m] = v;
                if ((m & 1) == 0) ri[m >> 1] = b;
                else              ri[m >> 1] |= (b << 16);
            }
        }
        __syncthreads();
    }
    if (tid < ROWS_PER_WG * I_DIM) {
        int rr = tid / I_DIM, c = tid % I_DIM;
        s_win[rr][c] = Win[(size_t)(row0 + rr) * I_DIM + c];
    }
    __syncthreads();

    // wave-poll setup: wave w deposits h[w*256 .. w*256+255] = output of
    // source WGs [w*4, w*4+4). Lanes 0-3 poll one flag line each.
    const int  src_wg  = (wave << 2) + (lane & 3);
    const bool poller  = (lane < 4);
    const unsigned* fp = &g_flag[src_wg << 5];

    // ---------- time loop ----------
    for (int t = 0; t < T_STEPS; ++t) {
        // prefetch x_t (issued early; same values/order)
        const float4* xp = (const float4*)(x + (size_t)t * I_DIM);
        const float4 xa = xp[0];
        const float4 xb = xp[1];

        if (t > 0) {
            const unsigned ut = (unsigned)t;
            for (;;) {
                unsigned v = poller
                    ? __hip_atomic_load(fp, __ATOMIC_RELAXED,
                                        __HIP_MEMORY_SCOPE_SYSTEM)
                    : ut;
                if (__all(v >= ut)) break;
                __builtin_amdgcn_s_sleep(1);
            }
            // one-shot bypass read of my 16 B of h_{t-1}
            const v4f* bp = (const v4f*)(g_hist + (size_t)(t - 1) * R_DIM
                                         + (size_t)tid * 4);
            v4f r0;
            asm volatile(
                "global_load_dwordx4 %0, %1, off sc0 sc1\n\t"
                "s_waitcnt vmcnt(0)"
                : "=v"(r0)
                : "v"(bp)
                : "memory");
            *(v4f*)(s_h + (size_t)tid * 4) = r0;
            __syncthreads();
        }

        // sparse row-dot from REGISTERS: slot order == stride-16 entry order
        float acc = 0.0f;
        if (t > 0) {
            #pragma unroll
            for (int m = 0; m < NS; ++m) {
                const unsigned ba = (m & 1) ? (ri[m >> 1] >> 16)
                                            : (ri[m >> 1] & 0xffffu);
                const float hv = *(const float*)((const char*)s_h + ba);
                acc += rv[m] * hv;
            }
        }
        acc += __shfl_xor(acc, 8, 16);
        acc += __shfl_xor(acc, 4, 16);
        acc += __shfl_xor(acc, 2, 16);
        acc += __shfl_xor(acc, 1, 16);

        if (sub == 0) {
            float a = acc;
            a += s_win[row16][0] * xa.x;
            a += s_win[row16][1] * xa.y;
            a += s_win[row16][2] * xa.z;
            a += s_win[row16][3] * xa.w;
            a += s_win[row16][4] * xb.x;
            a += s_win[row16][5] * xb.y;
            a += s_win[row16][6] * xb.z;
            a += s_win[row16][7] * xb.w;
            float h = tanhf(a);
            __hip_atomic_store(&g_hist[(size_t)t * R_DIM + row0 + row16], h,
                               __ATOMIC_RELAXED, __HIP_MEMORY_SCOPE_SYSTEM);
        }
        // release: drain own stores (acked at MALL), join WG, publish flag
        asm volatile("s_waitcnt vmcnt(0)" ::: "memory");
        __syncthreads();
        if (tid == 0)
            __hip_atomic_store(&g_flag[wg << 5], (unsigned)(t + 1),
                               __ATOMIC_RELAXED, __HIP_MEMORY_SCOPE_SYSTEM);
    }
}

// y_t = Wout h_t + b, one wave per timestep; accumulation order as R4..R12.
__global__ void esn_out_kernel(const float* __restrict__ Wout_w,
                               const float* __restrict__ Wout_b,
                               float* __restrict__ out) {
    const int t = blockIdx.x;
    const int lane = threadIdx.x;  // 64 threads
    const float* hp = g_hist + (size_t)t * R_DIM;
    float acc[O_DIM];
    #pragma unroll
    for (int o = 0; o < O_DIM; ++o) acc[o] = 0.0f;
    for (int i = lane; i < R_DIM; i += 256) {   // 16 iters, 4 indep loads each
        float h0 = __hip_atomic_load(hp + i,       __ATOMIC_RELAXED, __HIP_MEMORY_SCOPE_SYSTEM);
        float h1 = __hip_atomic_load(hp + i + 64,  __ATOMIC_RELAXED, __HIP_MEMORY_SCOPE_SYSTEM);
        float h2 = __hip_atomic_load(hp + i + 128, __ATOMIC_RELAXED, __HIP_MEMORY_SCOPE_SYSTEM);
        float h3 = __hip_atomic_load(hp + i + 192, __ATOMIC_RELAXED, __HIP_MEMORY_SCOPE_SYSTEM);
        #pragma unroll
        for (int o = 0; o < O_DIM; ++o) acc[o] += h0 * Wout_w[(size_t)o * R_DIM + i];
        #pragma unroll
        for (int o = 0; o < O_DIM; ++o) acc[o] += h1 * Wout_w[(size_t)o * R_DIM + i + 64];
        #pragma unroll
        for (int o = 0; o < O_DIM; ++o) acc[o] += h2 * Wout_w[(size_t)o * R_DIM + i + 128];
        #pragma unroll
        for (int o = 0; o < O_DIM; ++o) acc[o] += h3 * Wout_w[(size_t)o * R_DIM + i + 192];
    }
    #pragma unroll
    for (int o = 0; o < O_DIM; ++o) {
        float a = acc[o];
        a += __shfl_xor(a, 32);
        a += __shfl_xor(a, 16);
        a += __shfl_xor(a, 8);
        a += __shfl_xor(a, 4);
        a += __shfl_xor(a, 2);
        a += __shfl_xor(a, 1);
        if (lane == 0) out[(size_t)t * O_DIM + o] = a + Wout_b[o];
    }
}

extern "C" void kernel_launch(void* const* d_in, const int* in_sizes, int n_in,
                              void* d_out, int out_size, void* d_ws, size_t ws_size,
                              hipStream_t stream) {
    const float* x    = (const float*)d_in[0];   // [1,2048,8]
    const float* Win  = (const float*)d_in[1];   // [4096,8]
    const float* W    = (const float*)d_in[2];   // [4096,4096]
    const float* Ww   = (const float*)d_in[3];   // [8,4096]
    const float* Wb   = (const float*)d_in[4];   // [8]
    float* out = (float*)d_out;                  // [1,2048,8]

    hipLaunchKernelGGL(esn_init_kernel, dim3(1), dim3(256), 0, stream);

    void* args[] = { (void*)&x, (void*)&Win, (void*)&W };
    hipLaunchCooperativeKernel((void*)esn_recur_kernel, dim3(NWG), dim3(BLOCK),
                               args, 0, stream);

    hipLaunchKernelGGL(esn_out_kernel, dim3(T_STEPS), dim3(64), 0, stream,
                       Ww, Wb, out);
}